// Round 16
// baseline (1436.677 us; speedup 1.0000x reference)
//
#include <hip/hip_runtime.h>
#include <math.h>

#define BB  256
#define TT  2048
#define VV  64
#define DD  50
#define HH  50
#define HIDN 100

// [tok][j] = seqFMA_d(embed[tok][d]*Wx[d][j]) + b_rnn[j]; cols 50..63 = 0.
__device__ float g_emWxb[VV * 64];
// [c][i] = W1[i][c], i 50..63 = 0 (contiguous 256B rows -> wide s_loads).
__device__ float g_W1T[HIDN * 64];

// ---------------------------------------------------------------------------
// XLA/Eigen fast-tanh, FMA-contracted Horner. BIT-EXACT with the reference
// trajectory (R6-R15 pass, absmax 0.015625). Do not touch.
// ---------------------------------------------------------------------------
__device__ __forceinline__ float xla_tanhf_fma(float x) {
#pragma clang fp contract(off)
  float ax = fabsf(x);
  float cx = fminf(fmaxf(x, -7.90531110763549805f), 7.90531110763549805f);
  float x2 = cx * cx;
  float p = -2.76076847742355e-16f;
  p = fmaf(x2, p, 2.00018790482477e-13f);
  p = fmaf(x2, p, -8.60467152213735e-11f);
  p = fmaf(x2, p, 5.12229709037114e-08f);
  p = fmaf(x2, p, 1.48572235717979e-05f);
  p = fmaf(x2, p, 6.37261928875436e-04f);
  p = fmaf(x2, p, 4.89352455891786e-03f);
  p = cx * p;
  float q = 1.19825839466702e-06f;
  q = fmaf(x2, q, 1.18534705686654e-04f);
  q = fmaf(x2, q, 2.26843463243900e-03f);
  q = fmaf(x2, q, 4.89352518554385e-03f);
  float r = p / q;
  return (ax < 0.0004f) ? x : r;
}

// ---------------------------------------------------------------------------
// K1: xp table, Eigen-gemm bit-emulation (unchanged from passing R6).
// ---------------------------------------------------------------------------
__global__ __launch_bounds__(256) void prep_kernel(
    const float* __restrict__ embed, const float* __restrict__ Wx,
    const float* __restrict__ b_rnn) {
#pragma clang fp contract(off)
  int o = blockIdx.x * 256 + threadIdx.x;
  if (o >= VV * 64) return;
  int v = o >> 6, j = o & 63;
  float val = 0.f;
  if (j < HH) {
    float s = 0.f;
    for (int d = 0; d < DD; ++d)
      s = fmaf(embed[v * DD + d], Wx[d * HH + j], s);
    val = s + b_rnn[j];
  }
  g_emWxb[o] = val;
}

// K1b: W1 transpose (pure data movement, bit-exact trivially).
__global__ __launch_bounds__(256) void prep2_kernel(const float* __restrict__ W1) {
  int o = blockIdx.x * 256 + threadIdx.x;
  if (o >= HIDN * 64) return;
  int c = o >> 6, i = o & 63;
  g_W1T[o] = (i < HH) ? W1[i * HIDN + c] : 0.f;
}

// ---------------------------------------------------------------------------
// K2: recurrence, TWO ROWS PER WAVE (software dual-threading).
// rnn is latency-bound (VALUBusy 12.8%): per step = bcast ~180 + 50-dep-FMA
// 200 + tanh/div ~100. A second independent row's chain interleaves into the
// dependency bubbles (chains independent -> ~2cyc/FMA issue; both broadcasts
// queue on DS concurrently; tanh/divs interleave). whcol registers SHARED.
// Per-row arithmetic textually unchanged -> bit-identical (chaos gain 1.3e7;
// absmax must stay exactly 0.015625). Grid = BB/2 = 128 blocks.
// ---------------------------------------------------------------------------
__global__ __launch_bounds__(64) void rnn_kernel(
    const int* __restrict__ inputs, const float* __restrict__ Wh,
    float* hs) {
#pragma clang fp contract(off)
  const int b2 = blockIdx.x;           // row pair: rows 2*b2, 2*b2+1
  const int lane = threadIdx.x;

  __shared__ __align__(16) float emw[VV * 64];   // 16 KB
  __shared__ int toksA[TT];                      // 8 KB
  __shared__ int toksB[TT];                      // 8 KB
  __shared__ __align__(16) float hshareA[64];
  __shared__ __align__(16) float hshareB[64];

  for (int o = lane; o < VV * 64; o += 64) emw[o] = g_emWxb[o];
  const int* rowA = inputs + (size_t)(2 * b2 + 0) * TT;
  const int* rowB = inputs + (size_t)(2 * b2 + 1) * TT;
  for (int t = lane; t < TT; t += 64) { toksA[t] = rowA[t]; toksB[t] = rowB[t]; }

  float whcol[HH];
#pragma unroll
  for (int i = 0; i < HH; ++i)
    whcol[i] = (lane < HH) ? Wh[i * HH + lane] : 0.f;

  hshareA[lane] = 0.f;
  hshareB[lane] = 0.f;
  __syncthreads();      // once (staging)

  float* outA = hs + (size_t)(2 * b2 + 0) * TT * 64;
  float* outB = hs + (size_t)(2 * b2 + 1) * TT * 64;
  float xpA = emw[toksA[0] * 64 + lane];
  float xpB = emw[toksB[0] * 64 + lane];
  const float4* hpA = reinterpret_cast<const float4*>(hshareA);
  const float4* hpB = reinterpret_cast<const float4*>(hshareB);

#define FMA4R(acc, v, base)                       \
  acc = fmaf((v).x, whcol[(base) + 0], acc);      \
  acc = fmaf((v).y, whcol[(base) + 1], acc);      \
  acc = fmaf((v).z, whcol[(base) + 2], acc);      \
  acc = fmaf((v).w, whcol[(base) + 3], acc);

  for (int t = 0; t < TT; ++t) {
    // broadcasts for both rows (DS queue, in-order returns)
    float4 hqA[13], hqB[13];
#pragma unroll
    for (int q = 0; q < 13; ++q) hqA[q] = hpA[q];
#pragma unroll
    for (int q = 0; q < 13; ++q) hqB[q] = hpB[q];

    // two independent 50-FMA chains, source-interleaved (per-chain order = R6)
    float accA = 0.f, accB = 0.f;
#pragma unroll
    for (int q = 0; q < 12; ++q) {
      FMA4R(accA, hqA[q], 4 * q)
      FMA4R(accB, hqB[q], 4 * q)
    }
    accA = fmaf(hqA[12].x, whcol[48], accA);
    accB = fmaf(hqB[12].x, whcol[48], accB);
    accA = fmaf(hqA[12].y, whcol[49], accA);
    accB = fmaf(hqB[12].y, whcol[49], accB);
    float preA = xpA + accA;
    float preB = xpB + accB;

    // prefetch next xp for both rows (independent of h)
    int tn = (t + 1 < TT) ? (t + 1) : (TT - 1);
    float xpnA = emw[toksA[tn] * 64 + lane];
    float xpnB = emw[toksB[tn] * 64 + lane];

    float hA = xla_tanhf_fma(preA);   // independent -> interleaved by scheduler
    float hB = xla_tanhf_fma(preB);

    hshareA[lane] = hA;               // publish (same-wave RAW, no barrier)
    hshareB[lane] = hB;
    outA[(size_t)t * 64 + lane] = hA; // coalesced fire-and-forget
    outB[(size_t)t * 64 + lane] = hB;
    xpA = xpnA;
    xpB = xpnB;
  }
#undef FMA4R
}

// ---------------------------------------------------------------------------
// K3: MLP head — REVERTED to R14 (W1T scalar version; R15's packed-f32
// regressed ~2x from scalarization). One THREAD per (b,t) row, 4-way
// c-unroll; per-element chains bit-identical to R6. hs/out may alias ->
// NO restrict; thread r reads row r before writing it.
// ---------------------------------------------------------------------------
__global__ __launch_bounds__(256) void head_kernel(
    const float* hs, const float* __restrict__ b1,
    const float* __restrict__ W2, const float* __restrict__ b2,
    float* out) {
#pragma clang fp contract(off)
  const int r = blockIdx.x * 256 + threadIdx.x;  // 0 .. B*T-1
  const float* hrow = hs + (size_t)r * 64;

  float h[52];
#pragma unroll
  for (int q = 0; q < 13; ++q) {     // hrow is 256B-aligned
    float4 v = *reinterpret_cast<const float4*>(hrow + 4 * q);
    h[4 * q + 0] = v.x;
    h[4 * q + 1] = v.y;
    h[4 * q + 2] = v.z;
    h[4 * q + 3] = v.w;
  }

  float logit[VV];
#pragma unroll
  for (int jj = 0; jj < VV; ++jj) logit[jj] = b2[jj];

  for (int c = 0; c < HIDN; c += 4) {   // 25 iterations
    const float* w0 = g_W1T + (c + 0) * 64;
    const float* w1 = g_W1T + (c + 1) * 64;
    const float* w2c = g_W1T + (c + 2) * 64;
    const float* w3 = g_W1T + (c + 3) * 64;
    float a0 = 0.f, a1 = 0.f, a2 = 0.f, a3 = 0.f;
#pragma unroll
    for (int i = 0; i < HH; ++i) {      // 4 independent chains, per-chain order = R6
      a0 = fmaf(h[i], w0[i], a0);
      a1 = fmaf(h[i], w1[i], a1);
      a2 = fmaf(h[i], w2c[i], a2);
      a3 = fmaf(h[i], w3[i], a3);
    }
    a0 += b1[c + 0]; a0 = fmaxf(a0, 0.f);
    a1 += b1[c + 1]; a1 = fmaxf(a1, 0.f);
    a2 += b1[c + 2]; a2 = fmaxf(a2, 0.f);
    a3 += b1[c + 3]; a3 = fmaxf(a3, 0.f);
    const float* v0 = W2 + (c + 0) * VV;
    const float* v1 = W2 + (c + 1) * VV;
    const float* v2 = W2 + (c + 2) * VV;
    const float* v3 = W2 + (c + 3) * VV;
#pragma unroll
    for (int jj = 0; jj < VV; ++jj) {   // ascending-c update order = R6
      float acc = logit[jj];
      acc = fmaf(a0, v0[jj], acc);
      acc = fmaf(a1, v1[jj], acc);
      acc = fmaf(a2, v2[jj], acc);
      acc = fmaf(a3, v3[jj], acc);
      logit[jj] = acc;
    }
  }

  float* orow = out + (size_t)r * 64;
#pragma unroll
  for (int q = 0; q < 16; ++q) {
    float4 v;
    v.x = logit[4 * q + 0];
    v.y = logit[4 * q + 1];
    v.z = logit[4 * q + 2];
    v.w = logit[4 * q + 3];
    *reinterpret_cast<float4*>(orow + 4 * q) = v;
  }
}

// ---------------------------------------------------------------------------
extern "C" void kernel_launch(void* const* d_in, const int* in_sizes, int n_in,
                              void* d_out, int out_size, void* d_ws, size_t ws_size,
                              hipStream_t stream) {
  // Map inputs by element-count signature (dict order breaks the Wx/Wh tie).
  const void* p[9] = {nullptr};
  const int want[9] = {BB * TT, VV * DD, DD * HH, HH * HH, HH,
                       HH * HIDN, HIDN, HIDN * VV, VV};
  bool used[32] = {false};
  for (int k = 0; k < 9; ++k)
    for (int i = 0; i < n_in && i < 32; ++i)
      if (!used[i] && in_sizes[i] == want[k]) { p[k] = d_in[i]; used[i] = true; break; }

  const int*   inputs = (const int*)  p[0];
  const float* embed  = (const float*)p[1];
  const float* Wx     = (const float*)p[2];
  const float* Wh     = (const float*)p[3];
  const float* b_rnn  = (const float*)p[4];
  const float* W1     = (const float*)p[5];
  const float* b1     = (const float*)p[6];
  const float* W2     = (const float*)p[7];
  const float* b2     = (const float*)p[8];

  float* out = (float*)d_out;
  float* hs = (ws_size >= (size_t)(BB * TT * 64) * sizeof(float))
                  ? (float*)d_ws : out;

  prep_kernel<<<(VV * 64 + 255) / 256, 256, 0, stream>>>(embed, Wx, b_rnn);
  prep2_kernel<<<(HIDN * 64 + 255) / 256, 256, 0, stream>>>(W1);
  rnn_kernel<<<BB / 2, 64, 0, stream>>>(inputs, Wh, hs);
  head_kernel<<<(BB * TT) / 256, 256, 0, stream>>>(hs, b1, W2, b2, out);
}

// Round 17
// 745.208 us; speedup vs baseline: 1.9279x; 1.9279x over previous
//
#include <hip/hip_runtime.h>
#include <math.h>

#define BB  256
#define TT  2048
#define VV  64
#define DD  50
#define HH  50
#define HIDN 100

// [tok][j] = seqFMA_d(embed[tok][d]*Wx[d][j]) + b_rnn[j]; cols 50..63 = 0.
__device__ float g_emWxb[VV * 64];
// [c][i] = W1[i][c], i 50..63 = 0 (contiguous 256B rows -> wide s_loads).
__device__ float g_W1T[HIDN * 64];

// ---------------------------------------------------------------------------
// XLA/Eigen fast-tanh, FMA-contracted Horner. BIT-EXACT with the reference
// trajectory (R6-R16 pass, absmax 0.015625). Do not touch.
// ---------------------------------------------------------------------------
__device__ __forceinline__ float xla_tanhf_fma(float x) {
#pragma clang fp contract(off)
  float ax = fabsf(x);
  float cx = fminf(fmaxf(x, -7.90531110763549805f), 7.90531110763549805f);
  float x2 = cx * cx;
  float p = -2.76076847742355e-16f;
  p = fmaf(x2, p, 2.00018790482477e-13f);
  p = fmaf(x2, p, -8.60467152213735e-11f);
  p = fmaf(x2, p, 5.12229709037114e-08f);
  p = fmaf(x2, p, 1.48572235717979e-05f);
  p = fmaf(x2, p, 6.37261928875436e-04f);
  p = fmaf(x2, p, 4.89352455891786e-03f);
  p = cx * p;
  float q = 1.19825839466702e-06f;
  q = fmaf(x2, q, 1.18534705686654e-04f);
  q = fmaf(x2, q, 2.26843463243900e-03f);
  q = fmaf(x2, q, 4.89352518554385e-03f);
  float r = p / q;
  return (ax < 0.0004f) ? x : r;
}

// ---------------------------------------------------------------------------
// K1: xp table, Eigen-gemm bit-emulation (unchanged from passing R6).
// ---------------------------------------------------------------------------
__global__ __launch_bounds__(256) void prep_kernel(
    const float* __restrict__ embed, const float* __restrict__ Wx,
    const float* __restrict__ b_rnn) {
#pragma clang fp contract(off)
  int o = blockIdx.x * 256 + threadIdx.x;
  if (o >= VV * 64) return;
  int v = o >> 6, j = o & 63;
  float val = 0.f;
  if (j < HH) {
    float s = 0.f;
    for (int d = 0; d < DD; ++d)
      s = fmaf(embed[v * DD + d], Wx[d * HH + j], s);
    val = s + b_rnn[j];
  }
  g_emWxb[o] = val;
}

// K1b: W1 transpose (pure data movement, bit-exact trivially).
__global__ __launch_bounds__(256) void prep2_kernel(const float* __restrict__ W1) {
  int o = blockIdx.x * 256 + threadIdx.x;
  if (o >= HIDN * 64) return;
  int c = o >> 6, i = o & 63;
  g_W1T[o] = (i < HH) ? W1[i * HIDN + c] : 0.f;
}

// ---------------------------------------------------------------------------
// K2: recurrence, SPLIT-SOURCE broadcast (one row per wave — R16 showed wall
// time is bounded by one row's serial chain; multi-row/wave can't help).
// Cycle model of R11's 634/step: LDS write->read round-trip ~240 (in-order
// DS, no forwarding) + chain 200 + tanh ~150 + misc ~45. The chain consumes
// h_i at t=4i, so only EARLY values are latency-critical:
//   i=0..23  via BATCHED readlane of the live h register (no LDS round trip;
//            batched + sched_barrier avoids R8's per-pair SGPR hazard),
//   i=24..51 via 7 b128 LDS reads ISSUED FIRST (round-trip ~240 completes
//            just as the chain reaches FMA_24 at ~batch+96).
// Chain arithmetic order unchanged (ascending i, single acc) -> bit-exact;
// only operand TRANSPORT changes (readlane bits == LDS bits, verified R7-R9).
// Lanes >= 50: whcol=0, xp=0 -> h=0 -> hs cols 50..63 = 0.
// ---------------------------------------------------------------------------
__global__ __launch_bounds__(64) void rnn_kernel(
    const int* __restrict__ inputs, const float* __restrict__ Wh,
    float* hs) {
#pragma clang fp contract(off)
  const int b = blockIdx.x;
  const int lane = threadIdx.x;

  __shared__ __align__(16) float emw[VV * 64];  // 16 KB
  __shared__ int toks[TT];                      // 8 KB
  __shared__ __align__(16) float hshare[64];

  for (int o = lane; o < VV * 64; o += 64) emw[o] = g_emWxb[o];
  const int* rowp = inputs + (size_t)b * TT;
  for (int t = lane; t < TT; t += 64) toks[t] = rowp[t];

  float whcol[HH];
#pragma unroll
  for (int i = 0; i < HH; ++i)
    whcol[i] = (lane < HH) ? Wh[i * HH + lane] : 0.f;

  hshare[lane] = 0.f;   // h(-1) = 0
  __syncthreads();      // once (staging)

  float* outp = hs + (size_t)b * TT * 64;
  float h = 0.f;
  float xp = emw[toks[0] * 64 + lane];
  const float4* hp = reinterpret_cast<const float4*>(hshare);

  for (int t = 0; t < TT; ++t) {
    // LDS portion first: i=24..51 (7 b128) — DS round-trip starts immediately
    float4 hq[7];
#pragma unroll
    for (int q = 0; q < 7; ++q) hq[q] = hp[q + 6];

    // register portion: i=0..23 via batched readlane of live h (no LDS)
    float hv[24];
#pragma unroll
    for (int i = 0; i < 24; ++i)
      hv[i] = __int_as_float(__builtin_amdgcn_readlane(__float_as_int(h), i));
    __builtin_amdgcn_sched_barrier(0);   // batch stays ABOVE the chain (R8 lesson)

    // the 50-FMA chain: ascending i, single accumulator — bit-exact order
    float acc = 0.f;
#pragma unroll
    for (int i = 0; i < 24; ++i)
      acc = fmaf(hv[i], whcol[i], acc);
#pragma unroll
    for (int q = 0; q < 6; ++q) {
      acc = fmaf(hq[q].x, whcol[24 + 4 * q + 0], acc);
      acc = fmaf(hq[q].y, whcol[24 + 4 * q + 1], acc);
      acc = fmaf(hq[q].z, whcol[24 + 4 * q + 2], acc);
      acc = fmaf(hq[q].w, whcol[24 + 4 * q + 3], acc);
    }
    acc = fmaf(hq[6].x, whcol[48], acc);
    acc = fmaf(hq[6].y, whcol[49], acc);
    float pre = xp + acc;

    // prefetch next xp (independent of h; overlaps tanh)
    int tn = toks[(t + 1 < TT) ? (t + 1) : (TT - 1)];
    float xpn = emw[tn * 64 + lane];

    h = xla_tanhf_fma(pre);
    hshare[lane] = h;                  // publish i>=24 source (same-wave RAW)
    outp[(size_t)t * 64 + lane] = h;   // coalesced fire-and-forget
    xp = xpn;
  }
}

// ---------------------------------------------------------------------------
// K3: MLP head — R14 version, FROZEN (known 175us; R15's packed experiment
// regressed, R16 kept this). One THREAD per (b,t) row, 4-way c-unroll;
// per-element chains bit-identical to R6 (absmax must stay exactly
// 0.015625). hs/out may alias -> NO restrict.
// ---------------------------------------------------------------------------
__global__ __launch_bounds__(256) void head_kernel(
    const float* hs, const float* __restrict__ b1,
    const float* __restrict__ W2, const float* __restrict__ b2,
    float* out) {
#pragma clang fp contract(off)
  const int r = blockIdx.x * 256 + threadIdx.x;  // 0 .. B*T-1
  const float* hrow = hs + (size_t)r * 64;

  float h[52];
#pragma unroll
  for (int q = 0; q < 13; ++q) {     // hrow is 256B-aligned
    float4 v = *reinterpret_cast<const float4*>(hrow + 4 * q);
    h[4 * q + 0] = v.x;
    h[4 * q + 1] = v.y;
    h[4 * q + 2] = v.z;
    h[4 * q + 3] = v.w;
  }

  float logit[VV];
#pragma unroll
  for (int jj = 0; jj < VV; ++jj) logit[jj] = b2[jj];

  for (int c = 0; c < HIDN; c += 4) {   // 25 iterations
    const float* w0 = g_W1T + (c + 0) * 64;
    const float* w1 = g_W1T + (c + 1) * 64;
    const float* w2c = g_W1T + (c + 2) * 64;
    const float* w3 = g_W1T + (c + 3) * 64;
    float a0 = 0.f, a1 = 0.f, a2 = 0.f, a3 = 0.f;
#pragma unroll
    for (int i = 0; i < HH; ++i) {      // 4 independent chains, per-chain order = R6
      a0 = fmaf(h[i], w0[i], a0);
      a1 = fmaf(h[i], w1[i], a1);
      a2 = fmaf(h[i], w2c[i], a2);
      a3 = fmaf(h[i], w3[i], a3);
    }
    a0 += b1[c + 0]; a0 = fmaxf(a0, 0.f);
    a1 += b1[c + 1]; a1 = fmaxf(a1, 0.f);
    a2 += b1[c + 2]; a2 = fmaxf(a2, 0.f);
    a3 += b1[c + 3]; a3 = fmaxf(a3, 0.f);
    const float* v0 = W2 + (c + 0) * VV;
    const float* v1 = W2 + (c + 1) * VV;
    const float* v2 = W2 + (c + 2) * VV;
    const float* v3 = W2 + (c + 3) * VV;
#pragma unroll
    for (int jj = 0; jj < VV; ++jj) {   // ascending-c update order = R6
      float acc = logit[jj];
      acc = fmaf(a0, v0[jj], acc);
      acc = fmaf(a1, v1[jj], acc);
      acc = fmaf(a2, v2[jj], acc);
      acc = fmaf(a3, v3[jj], acc);
      logit[jj] = acc;
    }
  }

  float* orow = out + (size_t)r * 64;
#pragma unroll
  for (int q = 0; q < 16; ++q) {
    float4 v;
    v.x = logit[4 * q + 0];
    v.y = logit[4 * q + 1];
    v.z = logit[4 * q + 2];
    v.w = logit[4 * q + 3];
    *reinterpret_cast<float4*>(orow + 4 * q) = v;
  }
}

// ---------------------------------------------------------------------------
extern "C" void kernel_launch(void* const* d_in, const int* in_sizes, int n_in,
                              void* d_out, int out_size, void* d_ws, size_t ws_size,
                              hipStream_t stream) {
  // Map inputs by element-count signature (dict order breaks the Wx/Wh tie).
  const void* p[9] = {nullptr};
  const int want[9] = {BB * TT, VV * DD, DD * HH, HH * HH, HH,
                       HH * HIDN, HIDN, HIDN * VV, VV};
  bool used[32] = {false};
  for (int k = 0; k < 9; ++k)
    for (int i = 0; i < n_in && i < 32; ++i)
      if (!used[i] && in_sizes[i] == want[k]) { p[k] = d_in[i]; used[i] = true; break; }

  const int*   inputs = (const int*)  p[0];
  const float* embed  = (const float*)p[1];
  const float* Wx     = (const float*)p[2];
  const float* Wh     = (const float*)p[3];
  const float* b_rnn  = (const float*)p[4];
  const float* W1     = (const float*)p[5];
  const float* b1     = (const float*)p[6];
  const float* W2     = (const float*)p[7];
  const float* b2     = (const float*)p[8];

  float* out = (float*)d_out;
  float* hs = (ws_size >= (size_t)(BB * TT * 64) * sizeof(float))
                  ? (float*)d_ws : out;

  prep_kernel<<<(VV * 64 + 255) / 256, 256, 0, stream>>>(embed, Wx, b_rnn);
  prep2_kernel<<<(HIDN * 64 + 255) / 256, 256, 0, stream>>>(W1);
  rnn_kernel<<<BB, 64, 0, stream>>>(inputs, Wh, hs);
  head_kernel<<<(BB * TT) / 256, 256, 0, stream>>>(hs, b1, W2, b2, out);
}